// Round 3
// baseline (961.949 us; speedup 1.0000x reference)
//
#include <hip/hip_runtime.h>
#include <stdint.h>

typedef unsigned short u16;
typedef short s16x8 __attribute__((ext_vector_type(8)));
typedef unsigned short u16x8 __attribute__((ext_vector_type(8)));
typedef float f32x4 __attribute__((ext_vector_type(4)));

#define S_LEN 2048
#define NBATCH 2
#define HID 3584
#define NH 28
#define NKV 4
#define HD 128
#define QSZ 3584
#define KVSZ 512
#define QKV_N 4608
#define RSCALE 0.08838834764831845f  // 128^-0.5

__device__ __forceinline__ u16 f2bf(float f) {
    union { float f; uint32_t u; } x; x.f = f;
    uint32_t r = x.u + 0x7FFF + ((x.u >> 16) & 1);
    return (u16)(r >> 16);
}
__device__ __forceinline__ float bf2f(u16 u) {
    union { uint32_t u; float f; } x; x.u = ((uint32_t)u) << 16;
    return x.f;
}
__device__ __forceinline__ void async_load16(const u16* g, u16* l) {
    __builtin_amdgcn_global_load_lds((const __attribute__((address_space(1))) void*)g,
                                     (__attribute__((address_space(3))) void*)l, 16, 0, 0);
}

// ---------------- fp32 -> bf16 convert ----------------
__global__ __launch_bounds__(256) void cvt_bf16_kernel(const float* __restrict__ in,
                                                       u16* __restrict__ out, int n4) {
    int i = blockIdx.x * 256 + threadIdx.x;
    if (i >= n4) return;
    float4 v = ((const float4*)in)[i];
    ushort4 o;
    o.x = f2bf(v.x); o.y = f2bf(v.y); o.z = f2bf(v.z); o.w = f2bf(v.w);
    ((ushort4*)out)[i] = o;
}

// ---------------- transpose + convert: out[c][r] = bf16(in[r][c]) ----------------
__global__ __launch_bounds__(256) void transpose_cvt_kernel(const float* __restrict__ in,
                                                            u16* __restrict__ out, int R, int C) {
    __shared__ float tile[32][33];
    int r0 = blockIdx.y * 32, c0 = blockIdx.x * 32;
    int t = threadIdx.x;
    int tr = t >> 3, tc = (t & 7) * 4;
    float4 v = *(const float4*)&in[(size_t)(r0 + tr) * C + c0 + tc];
    tile[tr][tc + 0] = v.x; tile[tr][tc + 1] = v.y;
    tile[tr][tc + 2] = v.z; tile[tr][tc + 3] = v.w;
    __syncthreads();
    ushort4 o;
    o.x = f2bf(tile[tc + 0][tr]);
    o.y = f2bf(tile[tc + 1][tr]);
    o.z = f2bf(tile[tc + 2][tr]);
    o.w = f2bf(tile[tc + 3][tr]);
    *(ushort4*)&out[(size_t)(c0 + tr) * R + r0 + tc] = o;
}

// ---------------- bf16 MFMA GEMM: C[M,N] = A[M,K] * Bt[N,K]^T (+bias) ----------------
template <bool BIAS, bool OUTBF16>
__global__ __launch_bounds__(256) void gemm_kernel(const u16* __restrict__ A,
                                                   const u16* __restrict__ Bt,
                                                   const float* __restrict__ bias,
                                                   void* __restrict__ Cout,
                                                   int M, int N, int K) {
    __shared__ __align__(16) u16 As[128 * 64];
    __shared__ __align__(16) u16 Bs[128 * 64];
    int t = threadIdx.x;
    int w = t >> 6, l = t & 63;
    int lane16 = l & 15, quad = l >> 4;
    int m0 = blockIdx.y * 128, n0 = blockIdx.x * 128;
    int wm = (w >> 1) * 64, wn = (w & 1) * 64;

    f32x4 z = {0.f, 0.f, 0.f, 0.f};
    f32x4 acc[4][4];
#pragma unroll
    for (int i = 0; i < 4; ++i)
#pragma unroll
        for (int j = 0; j < 4; ++j) acc[i][j] = z;

    int srow = l >> 3;
    int scol = l & 7;
    int nk = K >> 6;
    for (int kt = 0; kt < nk; ++kt) {
#pragma unroll
        for (int j = 0; j < 4; ++j) {
            int seg = w * 4 + j;
            int row = seg * 8 + srow;
            int cg = scol ^ (row & 7);
            async_load16(A + (size_t)(m0 + row) * K + kt * 64 + cg * 8, As + seg * 512);
        }
#pragma unroll
        for (int j = 0; j < 4; ++j) {
            int seg = w * 4 + j;
            int row = seg * 8 + srow;
            int cg = scol ^ (row & 7);
            async_load16(Bt + (size_t)(n0 + row) * K + kt * 64 + cg * 8, Bs + seg * 512);
        }
        __syncthreads();
#pragma unroll
        for (int ks = 0; ks < 2; ++ks) {
            s16x8 af[4], bf[4];
#pragma unroll
            for (int mi = 0; mi < 4; ++mi) {
                int r = wm + mi * 16 + lane16;
                int ch = (ks * 4 + quad) ^ (r & 7);
                af[mi] = *(const s16x8*)&As[r * 64 + ch * 8];
            }
#pragma unroll
            for (int ni = 0; ni < 4; ++ni) {
                int r = wn + ni * 16 + lane16;
                int ch = (ks * 4 + quad) ^ (r & 7);
                bf[ni] = *(const s16x8*)&Bs[r * 64 + ch * 8];
            }
#pragma unroll
            for (int mi = 0; mi < 4; ++mi)
#pragma unroll
                for (int ni = 0; ni < 4; ++ni)
                    acc[mi][ni] = __builtin_amdgcn_mfma_f32_16x16x32_bf16(af[mi], bf[ni], acc[mi][ni], 0, 0, 0);
        }
        __syncthreads();
    }
#pragma unroll
    for (int ni = 0; ni < 4; ++ni) {
        int col = n0 + wn + ni * 16 + lane16;
        float bv = BIAS ? bias[col] : 0.0f;
#pragma unroll
        for (int mi = 0; mi < 4; ++mi) {
#pragma unroll
            for (int r = 0; r < 4; ++r) {
                int rowg = m0 + wm + mi * 16 + quad * 4 + r;
                float v = acc[mi][ni][r] + bv;
                if (OUTBF16)
                    ((u16*)Cout)[(size_t)rowg * N + col] = f2bf(v);
                else
                    ((float*)Cout)[(size_t)rowg * N + col] = v;
            }
        }
    }
}

// ---------------- RoPE (Q,K only; V handled by vtrans_kernel) ----------------
__global__ __launch_bounds__(256) void rope_kernel(const u16* __restrict__ qkv,
                                                   const int* __restrict__ positions,
                                                   u16* __restrict__ Q, u16* __restrict__ Kout) {
    int row = blockIdx.x;           // b*S + s
    int b = row >> 11, s = row & 2047;
    int t = threadIdx.x;
    int i = t & 63;
    int g = t >> 6;
    float pos = (float)positions[row];
    float freq = exp2f((float)(2 * i) * (-13.287712379549449f / 128.0f));
    float ang = pos * freq;
    float sn, cs;
    sincosf(ang, &sn, &cs);
    const u16* qrow = qkv + (size_t)row * QKV_N;
#pragma unroll
    for (int hh = 0; hh < 7; ++hh) {
        int h = g * 7 + hh;
        float x1 = bf2f(qrow[h * HD + i]);
        float x2 = bf2f(qrow[h * HD + 64 + i]);
        u16* qo = Q + ((size_t)(b * NH + h) * S_LEN + s) * HD;
        qo[i]      = f2bf((x1 * cs - x2 * sn) * RSCALE);
        qo[64 + i] = f2bf((x2 * cs + x1 * sn) * RSCALE);
    }
    {
        float x1 = bf2f(qrow[QSZ + g * HD + i]);
        float x2 = bf2f(qrow[QSZ + g * HD + 64 + i]);
        u16* ko = Kout + ((size_t)(b * NKV + g) * S_LEN + s) * HD;
        ko[i]      = f2bf(x1 * cs - x2 * sn);
        ko[64 + i] = f2bf(x2 * cs + x1 * sn);
    }
}

// ---------------- V transpose: qkv[:, QSZ+KVSZ:] -> Vt[b][c][s] (u16, LDS-tiled) ----------------
__global__ __launch_bounds__(256) void vtrans_kernel(const u16* __restrict__ qkv,
                                                     u16* __restrict__ Vt) {
    __shared__ u16 T[64 * 72];
    int t = threadIdx.x;
    int c0 = blockIdx.x * 64, s0 = blockIdx.y * 64, b = blockIdx.z;
    const u16* src = qkv + (size_t)b * 2048 * QKV_N + QSZ + KVSZ + c0;
#pragma unroll
    for (int i = 0; i < 2; ++i) {
        int idx = i * 256 + t;
        int sr = idx >> 3, ch = idx & 7;
        u16x8 v = *(const u16x8*)&src[(size_t)(s0 + sr) * QKV_N + ch * 8];
#pragma unroll
        for (int j = 0; j < 8; ++j) T[(ch * 8 + j) * 72 + sr] = v[j];
    }
    __syncthreads();
    u16* dst = Vt + (size_t)b * 512 * 2048;
#pragma unroll
    for (int i = 0; i < 2; ++i) {
        int idx = i * 256 + t;
        int cr = idx >> 3, ch = idx & 7;
        *(u16x8*)&dst[(size_t)(c0 + cr) * 2048 + s0 + ch * 8] = *(const u16x8*)&T[cr * 72 + ch * 8];
    }
}

// ---------------- flash attention (causal, GQA) ----------------
// BQ=128 (4 waves x 2 strips); statically-disjoint LDS double buffers so the
// prefetch global_load_lds is NOT vmcnt-serialized against the current tile's ds_reads.
#define ATTN_TILE(KT, KC, VC)                                                               \
    do {                                                                                    \
        f32x4 sa[2][4];                                                                     \
        _Pragma("unroll") for (int st = 0; st < 2; ++st)                                    \
            _Pragma("unroll") for (int ni = 0; ni < 4; ++ni) sa[st][ni] = z;                \
        _Pragma("unroll") for (int kd = 0; kd < 4; ++kd) {                                  \
            _Pragma("unroll") for (int ni = 0; ni < 4; ++ni) {                              \
                int srow = ni * 16 + lane16;                                                \
                int ch = (kd * 4 + quad) ^ lane16;                                          \
                s16x8 kf = *(const s16x8*)&(KC)[srow * 128 + ch * 8];                       \
                sa[0][ni] = __builtin_amdgcn_mfma_f32_16x16x32_bf16(qf[0][kd], kf, sa[0][ni], 0, 0, 0); \
                sa[1][ni] = __builtin_amdgcn_mfma_f32_16x16x32_bf16(qf[1][kd], kf, sa[1][ni], 0, 0, 0); \
            }                                                                               \
        }                                                                                   \
        bool domask = ((KT) >= nkt - 2);                                                    \
        _Pragma("unroll") for (int st = 0; st < 2; ++st) {                                  \
            if (domask) {                                                                   \
                _Pragma("unroll") for (int ni = 0; ni < 4; ++ni)                            \
                    _Pragma("unroll") for (int r = 0; r < 4; ++r) {                         \
                        int colg = (KT) * 64 + ni * 16 + lane16;                            \
                        int rowg = q0 + st * 64 + w * 16 + quad * 4 + r;                    \
                        if (colg > rowg) sa[st][ni][r] = -3.0e38f;                          \
                    }                                                                       \
            }                                                                               \
            float mx[4];                                                                    \
            _Pragma("unroll") for (int r = 0; r < 4; ++r) {                                 \
                mx[r] = fmaxf(fmaxf(sa[st][0][r], sa[st][1][r]), fmaxf(sa[st][2][r], sa[st][3][r])); \
                mx[r] = fmaxf(mx[r], __shfl_xor(mx[r], 1));                                 \
                mx[r] = fmaxf(mx[r], __shfl_xor(mx[r], 2));                                 \
                mx[r] = fmaxf(mx[r], __shfl_xor(mx[r], 4));                                 \
                mx[r] = fmaxf(mx[r], __shfl_xor(mx[r], 8));                                 \
            }                                                                               \
            float al[4], rs[4], p[4][4];                                                    \
            _Pragma("unroll") for (int r = 0; r < 4; ++r) {                                 \
                float mn = fmaxf(m_r[st][r], mx[r]);                                        \
                al[r] = __expf(m_r[st][r] - mn);                                            \
                m_r[st][r] = mn;                                                            \
                rs[r] = 0.f;                                                                \
            }                                                                               \
            _Pragma("unroll") for (int ni = 0; ni < 4; ++ni)                                \
                _Pragma("unroll") for (int r = 0; r < 4; ++r) {                             \
                    p[ni][r] = __expf(sa[st][ni][r] - m_r[st][r]);                          \
                    rs[r] += p[ni][r];                                                      \
                }                                                                           \
            _Pragma("unroll") for (int r = 0; r < 4; ++r) {                                 \
                rs[r] += __shfl_xor(rs[r], 1);                                              \
                rs[r] += __shfl_xor(rs[r], 2);                                              \
                rs[r] += __shfl_xor(rs[r], 4);                                              \
                rs[r] += __shfl_xor(rs[r], 8);                                              \
                l_r[st][r] = l_r[st][r] * al[r] + rs[r];                                    \
            }                                                                               \
            _Pragma("unroll") for (int i = 0; i < 8; ++i)                                   \
                _Pragma("unroll") for (int r = 0; r < 4; ++r) oacc[st][i][r] *= al[r];      \
            _Pragma("unroll") for (int ni = 0; ni < 4; ++ni)                                \
                _Pragma("unroll") for (int r = 0; r < 4; ++r)                               \
                    Pw[(quad * 4 + r) * 72 + ni * 16 + lane16] = f2bf(p[ni][r]);            \
            _Pragma("unroll") for (int ks = 0; ks < 2; ++ks) {                              \
                s16x8 pf = *(const s16x8*)&Pw[lane16 * 72 + ks * 32 + quad * 8];            \
                _Pragma("unroll") for (int ni2 = 0; ni2 < 8; ++ni2) {                       \
                    int vr = ni2 * 16 + lane16;                                             \
                    int ch = (ks * 4 + quad) ^ (vr & 7);                                    \
                    s16x8 vf = *(const s16x8*)&(VC)[vr * 64 + ch * 8];                      \
                    oacc[st][ni2] = __builtin_amdgcn_mfma_f32_16x16x32_bf16(pf, vf, oacc[st][ni2], 0, 0, 0); \
                }                                                                           \
            }                                                                               \
        }                                                                                   \
    } while (0)

__global__ __launch_bounds__(256) void attn_kernel(const u16* __restrict__ Q,
                                                   const u16* __restrict__ K,
                                                   const u16* __restrict__ Vt,
                                                   u16* __restrict__ O) {
    __shared__ __align__(16) u16 Ks0[64 * 128];
    __shared__ __align__(16) u16 Ks1[64 * 128];
    __shared__ __align__(16) u16 Vs0[128 * 64];
    __shared__ __align__(16) u16 Vs1[128 * 64];
    __shared__ __align__(16) u16 Ps[4 * 16 * 72];
    int qt = 15 - blockIdx.x;       // long blocks first
    int bh = blockIdx.y;
    int b = bh / NH, h = bh % NH;
    int hk = h / (NH / NKV);
    int q0 = qt * 128;
    int t = threadIdx.x, w = t >> 6, l = t & 63;
    int lane16 = l & 15, quad = l >> 4;
    const u16* Qb = Q + (size_t)(b * NH + h) * S_LEN * HD;
    const u16* Kb = K + (size_t)(b * NKV + hk) * S_LEN * HD;
    const u16* Vb = Vt + (size_t)(b * NKV + hk) * HD * S_LEN;

    s16x8 qf[2][4];
#pragma unroll
    for (int st = 0; st < 2; ++st) {
        int qrow = q0 + st * 64 + w * 16 + lane16;
#pragma unroll
        for (int kd = 0; kd < 4; ++kd)
            qf[st][kd] = *(const s16x8*)(Qb + (size_t)qrow * HD + kd * 32 + quad * 8);
    }

    f32x4 z = {0.f, 0.f, 0.f, 0.f};
    f32x4 oacc[2][8];
#pragma unroll
    for (int st = 0; st < 2; ++st)
#pragma unroll
        for (int i = 0; i < 8; ++i) oacc[st][i] = z;
    float m_r[2][4], l_r[2][4];
#pragma unroll
    for (int st = 0; st < 2; ++st)
#pragma unroll
        for (int r = 0; r < 4; ++r) { m_r[st][r] = -3.0e38f; l_r[st][r] = 0.f; }
    u16* Pw = Ps + w * (16 * 72);
    int nkt = 2 * qt + 2;

    auto stage = [&](int kt, u16* kdst, u16* vdst) {
#pragma unroll
        for (int j = 0; j < 4; ++j) {
            int seg = w * 4 + j;
            int row = seg * 4 + quad;
            int cg = lane16 ^ (row & 15);
            async_load16(Kb + (size_t)(kt * 64 + row) * HD + cg * 8, kdst + seg * 512);
        }
#pragma unroll
        for (int j = 0; j < 4; ++j) {
            int seg = w * 4 + j;
            int row = seg * 8 + (l >> 3);
            int cg = (l & 7) ^ (row & 7);
            async_load16(Vb + (size_t)row * S_LEN + kt * 64 + cg * 8, vdst + seg * 512);
        }
    };

    stage(0, Ks0, Vs0);
    __syncthreads();

    int kt = 0;
    while (true) {
        if (kt + 1 < nkt) stage(kt + 1, Ks1, Vs1);
        ATTN_TILE(kt, Ks0, Vs0);
        __syncthreads();
        ++kt; if (kt >= nkt) break;
        if (kt + 1 < nkt) stage(kt + 1, Ks0, Vs0);
        ATTN_TILE(kt, Ks1, Vs1);
        __syncthreads();
        ++kt; if (kt >= nkt) break;
    }

#pragma unroll
    for (int st = 0; st < 2; ++st)
#pragma unroll
        for (int r = 0; r < 4; ++r) l_r[st][r] = 1.0f / l_r[st][r];
#pragma unroll
    for (int st = 0; st < 2; ++st)
#pragma unroll
        for (int ni2 = 0; ni2 < 8; ++ni2)
#pragma unroll
            for (int r = 0; r < 4; ++r) {
                int rowg = q0 + st * 64 + w * 16 + quad * 4 + r;
                int colg = h * HD + ni2 * 16 + lane16;
                O[((size_t)b * S_LEN + rowg) * QSZ + colg] = f2bf(oacc[st][ni2][r] * l_r[st][r]);
            }
}

extern "C" void kernel_launch(void* const* d_in, const int* in_sizes, int n_in,
                              void* d_out, int out_size, void* d_ws, size_t ws_size,
                              hipStream_t stream) {
    const int* positions = (const int*)d_in[0];
    const float* hs = (const float*)d_in[1];
    const float* Wqkv = (const float*)d_in[2];
    const float* bqkv = (const float*)d_in[3];
    const float* Wo = (const float*)d_in[4];
    float* out = (float*)d_out;
    char* ws = (char*)d_ws;

    u16* hsb   = (u16*)(ws + 0);          // later reused as Q
    u16* Wqkvt = (u16*)(ws + 29360128);
    u16* Wot   = (u16*)(ws + 62390272);
    u16* qkv   = (u16*)(ws + 88080384);   // later reused as attn out
    u16* Kbuf  = (u16*)(ws + 125829120);
    u16* Vtb   = (u16*)(ws + 130023424);
    u16* Qbuf  = hsb;
    u16* attn  = qkv;

    hipLaunchKernelGGL(cvt_bf16_kernel, dim3(14336), dim3(256), 0, stream, hs, hsb, 3670016);
    hipLaunchKernelGGL(transpose_cvt_kernel, dim3(144, 112), dim3(256), 0, stream, Wqkv, Wqkvt, 3584, 4608);
    hipLaunchKernelGGL(transpose_cvt_kernel, dim3(112, 112), dim3(256), 0, stream, Wo, Wot, 3584, 3584);
    hipLaunchKernelGGL((gemm_kernel<true, true>), dim3(36, 32), dim3(256), 0, stream,
                       hsb, Wqkvt, bqkv, (void*)qkv, 4096, 4608, 3584);
    hipLaunchKernelGGL(rope_kernel, dim3(4096), dim3(256), 0, stream, qkv, positions, Qbuf, Kbuf);
    hipLaunchKernelGGL(vtrans_kernel, dim3(8, 32, 2), dim3(256), 0, stream, qkv, Vtb);
    hipLaunchKernelGGL(attn_kernel, dim3(16, 56), dim3(256), 0, stream, Qbuf, Kbuf, Vtb, attn);
    hipLaunchKernelGGL((gemm_kernel<false, false>), dim3(28, 32), dim3(256), 0, stream,
                       attn, Wot, (const float*)nullptr, (void*)out, 4096, 3584, 3584);
}

// Round 4
// 666.426 us; speedup vs baseline: 1.4434x; 1.4434x over previous
//
#include <hip/hip_runtime.h>
#include <stdint.h>

typedef unsigned short u16;
typedef short s16x8 __attribute__((ext_vector_type(8)));
typedef unsigned short u16x8 __attribute__((ext_vector_type(8)));
typedef float f32x4 __attribute__((ext_vector_type(4)));

#define S_LEN 2048
#define NBATCH 2
#define HID 3584
#define NH 28
#define NKV 4
#define HD 128
#define QSZ 3584
#define KVSZ 512
#define QKV_N 4608
#define RSCALE 0.08838834764831845f  // 128^-0.5

__device__ __forceinline__ u16 f2bf(float f) {
    union { float f; uint32_t u; } x; x.f = f;
    uint32_t r = x.u + 0x7FFF + ((x.u >> 16) & 1);
    return (u16)(r >> 16);
}
__device__ __forceinline__ float bf2f(u16 u) {
    union { uint32_t u; float f; } x; x.u = ((uint32_t)u) << 16;
    return x.f;
}
__device__ __forceinline__ void async_load16(const u16* g, u16* l) {
    __builtin_amdgcn_global_load_lds((const __attribute__((address_space(1))) void*)g,
                                     (__attribute__((address_space(3))) void*)l, 16, 0, 0);
}

// ---------------- fp32 -> bf16 convert ----------------
__global__ __launch_bounds__(256) void cvt_bf16_kernel(const float* __restrict__ in,
                                                       u16* __restrict__ out, int n4) {
    int i = blockIdx.x * 256 + threadIdx.x;
    if (i >= n4) return;
    float4 v = ((const float4*)in)[i];
    ushort4 o;
    o.x = f2bf(v.x); o.y = f2bf(v.y); o.z = f2bf(v.z); o.w = f2bf(v.w);
    ((ushort4*)out)[i] = o;
}

// ---------------- transpose + convert: out[c][r] = bf16(in[r][c]) ----------------
__global__ __launch_bounds__(256) void transpose_cvt_kernel(const float* __restrict__ in,
                                                            u16* __restrict__ out, int R, int C) {
    __shared__ float tile[32][33];
    int r0 = blockIdx.y * 32, c0 = blockIdx.x * 32;
    int t = threadIdx.x;
    int tr = t >> 3, tc = (t & 7) * 4;
    float4 v = *(const float4*)&in[(size_t)(r0 + tr) * C + c0 + tc];
    tile[tr][tc + 0] = v.x; tile[tr][tc + 1] = v.y;
    tile[tr][tc + 2] = v.z; tile[tr][tc + 3] = v.w;
    __syncthreads();
    ushort4 o;
    o.x = f2bf(tile[tc + 0][tr]);
    o.y = f2bf(tile[tc + 1][tr]);
    o.z = f2bf(tile[tc + 2][tr]);
    o.w = f2bf(tile[tc + 3][tr]);
    *(ushort4*)&out[(size_t)(c0 + tr) * R + r0 + tc] = o;
}

// ---------------- bf16 MFMA GEMM: C[M,N] = A[M,K] * Bt[N,K]^T (+bias) ----------------
template <bool BIAS, bool OUTBF16>
__global__ __launch_bounds__(256) void gemm_kernel(const u16* __restrict__ A,
                                                   const u16* __restrict__ Bt,
                                                   const float* __restrict__ bias,
                                                   void* __restrict__ Cout,
                                                   int M, int N, int K) {
    __shared__ __align__(16) u16 As[128 * 64];
    __shared__ __align__(16) u16 Bs[128 * 64];
    int t = threadIdx.x;
    int w = t >> 6, l = t & 63;
    int lane16 = l & 15, quad = l >> 4;
    int m0 = blockIdx.y * 128, n0 = blockIdx.x * 128;
    int wm = (w >> 1) * 64, wn = (w & 1) * 64;

    f32x4 z = {0.f, 0.f, 0.f, 0.f};
    f32x4 acc[4][4];
#pragma unroll
    for (int i = 0; i < 4; ++i)
#pragma unroll
        for (int j = 0; j < 4; ++j) acc[i][j] = z;

    int srow = l >> 3;
    int scol = l & 7;
    int nk = K >> 6;
    for (int kt = 0; kt < nk; ++kt) {
#pragma unroll
        for (int j = 0; j < 4; ++j) {
            int seg = w * 4 + j;
            int row = seg * 8 + srow;
            int cg = scol ^ (row & 7);
            async_load16(A + (size_t)(m0 + row) * K + kt * 64 + cg * 8, As + seg * 512);
        }
#pragma unroll
        for (int j = 0; j < 4; ++j) {
            int seg = w * 4 + j;
            int row = seg * 8 + srow;
            int cg = scol ^ (row & 7);
            async_load16(Bt + (size_t)(n0 + row) * K + kt * 64 + cg * 8, Bs + seg * 512);
        }
        __syncthreads();
#pragma unroll
        for (int ks = 0; ks < 2; ++ks) {
            s16x8 af[4], bf[4];
#pragma unroll
            for (int mi = 0; mi < 4; ++mi) {
                int r = wm + mi * 16 + lane16;
                int ch = (ks * 4 + quad) ^ (r & 7);
                af[mi] = *(const s16x8*)&As[r * 64 + ch * 8];
            }
#pragma unroll
            for (int ni = 0; ni < 4; ++ni) {
                int r = wn + ni * 16 + lane16;
                int ch = (ks * 4 + quad) ^ (r & 7);
                bf[ni] = *(const s16x8*)&Bs[r * 64 + ch * 8];
            }
#pragma unroll
            for (int mi = 0; mi < 4; ++mi)
#pragma unroll
                for (int ni = 0; ni < 4; ++ni)
                    acc[mi][ni] = __builtin_amdgcn_mfma_f32_16x16x32_bf16(af[mi], bf[ni], acc[mi][ni], 0, 0, 0);
        }
        __syncthreads();
    }
#pragma unroll
    for (int ni = 0; ni < 4; ++ni) {
        int col = n0 + wn + ni * 16 + lane16;
        float bv = BIAS ? bias[col] : 0.0f;
#pragma unroll
        for (int mi = 0; mi < 4; ++mi) {
#pragma unroll
            for (int r = 0; r < 4; ++r) {
                int rowg = m0 + wm + mi * 16 + quad * 4 + r;
                float v = acc[mi][ni][r] + bv;
                if (OUTBF16)
                    ((u16*)Cout)[(size_t)rowg * N + col] = f2bf(v);
                else
                    ((float*)Cout)[(size_t)rowg * N + col] = v;
            }
        }
    }
}

// ---------------- RoPE (Q,K only; V handled by vtrans_kernel) ----------------
__global__ __launch_bounds__(256) void rope_kernel(const u16* __restrict__ qkv,
                                                   const int* __restrict__ positions,
                                                   u16* __restrict__ Q, u16* __restrict__ Kout) {
    int row = blockIdx.x;           // b*S + s
    int b = row >> 11, s = row & 2047;
    int t = threadIdx.x;
    int i = t & 63;
    int g = t >> 6;
    float pos = (float)positions[row];
    float freq = exp2f((float)(2 * i) * (-13.287712379549449f / 128.0f));
    float ang = pos * freq;
    float sn, cs;
    sincosf(ang, &sn, &cs);
    const u16* qrow = qkv + (size_t)row * QKV_N;
#pragma unroll
    for (int hh = 0; hh < 7; ++hh) {
        int h = g * 7 + hh;
        float x1 = bf2f(qrow[h * HD + i]);
        float x2 = bf2f(qrow[h * HD + 64 + i]);
        u16* qo = Q + ((size_t)(b * NH + h) * S_LEN + s) * HD;
        qo[i]      = f2bf((x1 * cs - x2 * sn) * RSCALE);
        qo[64 + i] = f2bf((x2 * cs + x1 * sn) * RSCALE);
    }
    {
        float x1 = bf2f(qrow[QSZ + g * HD + i]);
        float x2 = bf2f(qrow[QSZ + g * HD + 64 + i]);
        u16* ko = Kout + ((size_t)(b * NKV + g) * S_LEN + s) * HD;
        ko[i]      = f2bf(x1 * cs - x2 * sn);
        ko[64 + i] = f2bf(x2 * cs + x1 * sn);
    }
}

// ---------------- V transpose: qkv[:, QSZ+KVSZ:] -> Vt[b][c][s] (u16, LDS-tiled) ----------------
__global__ __launch_bounds__(256) void vtrans_kernel(const u16* __restrict__ qkv,
                                                     u16* __restrict__ Vt) {
    __shared__ u16 T[64 * 72];
    int t = threadIdx.x;
    int c0 = blockIdx.x * 64, s0 = blockIdx.y * 64, b = blockIdx.z;
    const u16* src = qkv + (size_t)b * 2048 * QKV_N + QSZ + KVSZ + c0;
#pragma unroll
    for (int i = 0; i < 2; ++i) {
        int idx = i * 256 + t;
        int sr = idx >> 3, ch = idx & 7;
        u16x8 v = *(const u16x8*)&src[(size_t)(s0 + sr) * QKV_N + ch * 8];
#pragma unroll
        for (int j = 0; j < 8; ++j) T[(ch * 8 + j) * 72 + sr] = v[j];
    }
    __syncthreads();
    u16* dst = Vt + (size_t)b * 512 * 2048;
#pragma unroll
    for (int i = 0; i < 2; ++i) {
        int idx = i * 256 + t;
        int cr = idx >> 3, ch = idx & 7;
        *(u16x8*)&dst[(size_t)(c0 + cr) * 2048 + s0 + ch * 8] = *(const u16x8*)&T[cr * 72 + ch * 8];
    }
}

// ---------------- flash attention (causal, GQA-fused) ----------------
// Block = (b, hk, q-tile-pair). 512 threads = 8 waves. Waves 0-6 each own one
// q-head of the GQA group (7 heads share the staged K/V tile); wave 7 stages only.
// Each block does q-tiles p*32 and (63-p)*32 => exactly 33 k-iterations for every
// block (perfect balance; grid 256 = 1 block/CU). Staging = plain loads into regs
// issued one tile ahead, ds_write after compute barrier (latency hidden by compute).
__global__ __launch_bounds__(512, 2) void attn_kernel(const u16* __restrict__ Q,
                                                      const u16* __restrict__ K,
                                                      const u16* __restrict__ Vt,
                                                      u16* __restrict__ O) {
    __shared__ __align__(16) u16 Ks[64 * 128];
    __shared__ __align__(16) u16 Vs[128 * 64];
    __shared__ __align__(16) u16 Ps[7 * 16 * 72];
    int p = blockIdx.x;             // 0..31  (q-tile pair)
    int bh = blockIdx.y;            // b*4 + hk
    int b = bh >> 2, hk = bh & 3;
    int t = threadIdx.x, w = t >> 6, l = t & 63;
    int lane16 = l & 15, quad = l >> 4;
    const u16* Kb = K + (size_t)(b * NKV + hk) * S_LEN * HD;
    const u16* Vb = Vt + (size_t)(b * NKV + hk) * HD * S_LEN;
    int wc = (w < 7) ? w : 6;       // clamp so wave 7's pointer math stays in-bounds
    int h = hk * 7 + wc;
    const u16* Qb = Q + (size_t)(b * NH + h) * S_LEN * HD;
    u16* Pw = Ps + wc * (16 * 72);

    u16x8 kr[2], vr_[2];
    auto stageR = [&](int kt) {
#pragma unroll
        for (int j = 0; j < 2; ++j) {
            int idx = j * 512 + t;
            kr[j] = *(const u16x8*)&Kb[(size_t)(kt * 64 + (idx >> 4)) * HD + (idx & 15) * 8];
        }
#pragma unroll
        for (int j = 0; j < 2; ++j) {
            int idx = j * 512 + t;
            vr_[j] = *(const u16x8*)&Vb[(size_t)(idx >> 3) * S_LEN + kt * 64 + (idx & 7) * 8];
        }
    };
    auto dsw = [&]() {
#pragma unroll
        for (int j = 0; j < 2; ++j) {
            int idx = j * 512 + t;
            int row = idx >> 4, c = idx & 15;
            *(u16x8*)&Ks[row * 128 + (c ^ (row & 15)) * 8] = kr[j];
        }
#pragma unroll
        for (int j = 0; j < 2; ++j) {
            int idx = j * 512 + t;
            int row = idx >> 3, c = idx & 7;
            *(u16x8*)&Vs[row * 64 + (c ^ (row & 7)) * 8] = vr_[j];
        }
    };

    f32x4 z = {0.f, 0.f, 0.f, 0.f};

#pragma unroll 1
    for (int phase = 0; phase < 2; ++phase) {
        int q0 = (phase == 0) ? p * 32 : (63 - p) * 32;
        int nkt = (q0 >> 6) + 1;

        s16x8 qf[2][4];
        if (w < 7) {
#pragma unroll
            for (int st = 0; st < 2; ++st) {
                int qrow = q0 + st * 16 + lane16;
#pragma unroll
                for (int kd = 0; kd < 4; ++kd)
                    qf[st][kd] = *(const s16x8*)(Qb + (size_t)qrow * HD + kd * 32 + quad * 8);
            }
        }
        f32x4 oacc[2][8];
        float m_r[2][4], l_r[2][4];
#pragma unroll
        for (int st = 0; st < 2; ++st) {
#pragma unroll
            for (int i = 0; i < 8; ++i) oacc[st][i] = z;
#pragma unroll
            for (int r = 0; r < 4; ++r) { m_r[st][r] = -3.0e38f; l_r[st][r] = 0.f; }
        }

        stageR(0);
#pragma unroll 1
        for (int kt = 0; kt < nkt; ++kt) {
            __syncthreads();                 // all waves done reading previous tile
            dsw();                           // LDS <- regs (tile kt)
            __syncthreads();
            if (kt + 1 < nkt) stageR(kt + 1);  // issue next tile's global loads now
            if (w < 7) {
#pragma unroll
                for (int st = 0; st < 2; ++st) {
                    f32x4 sa[4];
                    sa[0] = z; sa[1] = z; sa[2] = z; sa[3] = z;
#pragma unroll
                    for (int kd = 0; kd < 4; ++kd) {
#pragma unroll
                        for (int ni = 0; ni < 4; ++ni) {
                            int srow = ni * 16 + lane16;
                            int ch = (kd * 4 + quad) ^ lane16;
                            s16x8 kf = *(const s16x8*)&Ks[srow * 128 + ch * 8];
                            sa[ni] = __builtin_amdgcn_mfma_f32_16x16x32_bf16(qf[st][kd], kf, sa[ni], 0, 0, 0);
                        }
                    }
                    if (kt == nkt - 1) {
#pragma unroll
                        for (int ni = 0; ni < 4; ++ni)
#pragma unroll
                            for (int r = 0; r < 4; ++r) {
                                int colg = kt * 64 + ni * 16 + lane16;
                                int rowg = q0 + st * 16 + quad * 4 + r;
                                if (colg > rowg) sa[ni][r] = -3.0e38f;
                            }
                    }
                    float mx[4];
#pragma unroll
                    for (int r = 0; r < 4; ++r) {
                        mx[r] = fmaxf(fmaxf(sa[0][r], sa[1][r]), fmaxf(sa[2][r], sa[3][r]));
                        mx[r] = fmaxf(mx[r], __shfl_xor(mx[r], 1));
                        mx[r] = fmaxf(mx[r], __shfl_xor(mx[r], 2));
                        mx[r] = fmaxf(mx[r], __shfl_xor(mx[r], 4));
                        mx[r] = fmaxf(mx[r], __shfl_xor(mx[r], 8));
                    }
                    float al[4], rs[4], pp[4][4];
#pragma unroll
                    for (int r = 0; r < 4; ++r) {
                        float mn = fmaxf(m_r[st][r], mx[r]);
                        al[r] = __expf(m_r[st][r] - mn);
                        m_r[st][r] = mn;
                        rs[r] = 0.f;
                    }
#pragma unroll
                    for (int ni = 0; ni < 4; ++ni)
#pragma unroll
                        for (int r = 0; r < 4; ++r) {
                            pp[ni][r] = __expf(sa[ni][r] - m_r[st][r]);
                            rs[r] += pp[ni][r];
                        }
#pragma unroll
                    for (int r = 0; r < 4; ++r) {
                        rs[r] += __shfl_xor(rs[r], 1);
                        rs[r] += __shfl_xor(rs[r], 2);
                        rs[r] += __shfl_xor(rs[r], 4);
                        rs[r] += __shfl_xor(rs[r], 8);
                        l_r[st][r] = l_r[st][r] * al[r] + rs[r];
                    }
#pragma unroll
                    for (int i = 0; i < 8; ++i)
#pragma unroll
                        for (int r = 0; r < 4; ++r) oacc[st][i][r] *= al[r];
                    // P: C-layout -> A-layout via per-wave LDS region
#pragma unroll
                    for (int ni = 0; ni < 4; ++ni)
#pragma unroll
                        for (int r = 0; r < 4; ++r)
                            Pw[(quad * 4 + r) * 72 + ni * 16 + lane16] = f2bf(pp[ni][r]);
#pragma unroll
                    for (int ks = 0; ks < 2; ++ks) {
                        s16x8 pf = *(const s16x8*)&Pw[lane16 * 72 + ks * 32 + quad * 8];
#pragma unroll
                        for (int ni2 = 0; ni2 < 8; ++ni2) {
                            int vr = ni2 * 16 + lane16;
                            int ch = (ks * 4 + quad) ^ (vr & 7);
                            s16x8 vf = *(const s16x8*)&Vs[vr * 64 + ch * 8];
                            oacc[st][ni2] = __builtin_amdgcn_mfma_f32_16x16x32_bf16(pf, vf, oacc[st][ni2], 0, 0, 0);
                        }
                    }
                }
            }
        }
        // epilogue for this q-tile
        if (w < 7) {
#pragma unroll
            for (int st = 0; st < 2; ++st) {
                float inv[4];
#pragma unroll
                for (int r = 0; r < 4; ++r) inv[r] = 1.0f / l_r[st][r];
#pragma unroll
                for (int ni2 = 0; ni2 < 8; ++ni2)
#pragma unroll
                    for (int r = 0; r < 4; ++r) {
                        int rowg = q0 + st * 16 + quad * 4 + r;
                        int colg = h * HD + ni2 * 16 + lane16;
                        O[((size_t)b * S_LEN + rowg) * QSZ + colg] = f2bf(oacc[st][ni2][r] * inv[r]);
                    }
            }
        }
    }
}

extern "C" void kernel_launch(void* const* d_in, const int* in_sizes, int n_in,
                              void* d_out, int out_size, void* d_ws, size_t ws_size,
                              hipStream_t stream) {
    const int* positions = (const int*)d_in[0];
    const float* hs = (const float*)d_in[1];
    const float* Wqkv = (const float*)d_in[2];
    const float* bqkv = (const float*)d_in[3];
    const float* Wo = (const float*)d_in[4];
    float* out = (float*)d_out;
    char* ws = (char*)d_ws;

    u16* hsb   = (u16*)(ws + 0);          // later reused as Q
    u16* Wqkvt = (u16*)(ws + 29360128);
    u16* Wot   = (u16*)(ws + 62390272);
    u16* qkv   = (u16*)(ws + 88080384);   // later reused as attn out
    u16* Kbuf  = (u16*)(ws + 125829120);
    u16* Vtb   = (u16*)(ws + 130023424);
    u16* Qbuf  = hsb;
    u16* attn  = qkv;

    hipLaunchKernelGGL(cvt_bf16_kernel, dim3(14336), dim3(256), 0, stream, hs, hsb, 3670016);
    hipLaunchKernelGGL(transpose_cvt_kernel, dim3(144, 112), dim3(256), 0, stream, Wqkv, Wqkvt, 3584, 4608);
    hipLaunchKernelGGL(transpose_cvt_kernel, dim3(112, 112), dim3(256), 0, stream, Wo, Wot, 3584, 3584);
    hipLaunchKernelGGL((gemm_kernel<true, true>), dim3(36, 32), dim3(256), 0, stream,
                       hsb, Wqkvt, bqkv, (void*)qkv, 4096, 4608, 3584);
    hipLaunchKernelGGL(rope_kernel, dim3(4096), dim3(256), 0, stream, qkv, positions, Qbuf, Kbuf);
    hipLaunchKernelGGL(vtrans_kernel, dim3(8, 32, 2), dim3(256), 0, stream, qkv, Vtb);
    hipLaunchKernelGGL(attn_kernel, dim3(32, 8), dim3(512), 0, stream, Qbuf, Kbuf, Vtb, attn);
    hipLaunchKernelGGL((gemm_kernel<false, false>), dim3(28, 32), dim3(256), 0, stream,
                       attn, Wot, (const float*)nullptr, (void*)out, 4096, 3584, 3584);
}